// Round 1
// baseline (259.579 us; speedup 1.0000x reference)
//
#include <hip/hip_runtime.h>

#define HH 299
#define WW 299
#define BORDER 3

__global__ __launch_bounds__(256) void crop_resize_kernel(
    const float* __restrict__ x,   // (S, 3, H, W)
    const int*   __restrict__ f,   // (S, G, 4)
    float*       __restrict__ out, // (S, G, 3, H, W)
    int S, int G)
{
    int blk = blockIdx.x;
    int row = blk % HH;
    int sg  = blk / HH;
    int gi  = sg % G;
    int si  = sg / G;

    const int* box = f + ((size_t)si * G + gi) * 4;
    int tlx = max(box[0] - BORDER, 0);
    int tly = max(box[1] - BORDER, 0);
    int brx = min(box[2] + BORDER, HH - 1);
    int bry = min(box[3] + BORDER, WW - 1);
    int hc = brx - tlx;   // in_extent along output dim-H (x axis)
    int wc = bry - tly;   // in_extent along output dim-W (y axis)

    // x-axis (row) source coords — uniform across the block
    float hf = (float)hc;
    float sx = ((row + 0.5f) * hf) / (float)HH - 0.5f;
    sx = fminf(fmaxf(sx, 0.0f), hf - 1.0f);
    int xi0 = (int)floorf(sx);
    xi0 = min(xi0, hc - 1);
    int xi1 = min(xi0 + 1, hc - 1);
    float fx = sx - (float)xi0;
    int gx0 = tlx + xi0;
    int gx1 = tlx + xi1;

    const float* img = x + (size_t)si * 3 * HH * WW;
    float* o = out + (((size_t)((size_t)si * G + gi) * 3) * HH + row) * WW;

    float wf = (float)wc;
    for (int j = threadIdx.x; j < WW; j += blockDim.x) {
        float sy = ((j + 0.5f) * wf) / (float)WW - 0.5f;
        sy = fminf(fmaxf(sy, 0.0f), wf - 1.0f);
        int yi0 = (int)floorf(sy);
        yi0 = min(yi0, wc - 1);
        int yi1 = min(yi0 + 1, wc - 1);
        float fy = sy - (float)yi0;
        int gy0 = tly + yi0;
        int gy1 = tly + yi1;

        float omfy = 1.0f - fy;
        float omfx = 1.0f - fx;

        #pragma unroll
        for (int c = 0; c < 3; ++c) {
            const float* ic = img + (size_t)c * HH * WW;
            float v00 = ic[(size_t)gx0 * WW + gy0];
            float v01 = ic[(size_t)gx0 * WW + gy1];
            float v10 = ic[(size_t)gx1 * WW + gy0];
            float v11 = ic[(size_t)gx1 * WW + gy1];
            float top = v00 * omfy + v01 * fy;
            float bot = v10 * omfy + v11 * fy;
            o[(size_t)c * HH * WW + j] = top * omfx + bot * fx;
        }
    }
}

extern "C" void kernel_launch(void* const* d_in, const int* in_sizes, int n_in,
                              void* d_out, int out_size, void* d_ws, size_t ws_size,
                              hipStream_t stream) {
    const float* x = (const float*)d_in[0];
    const int*   f = (const int*)d_in[1];
    float* out = (float*)d_out;

    int S = in_sizes[0] / (3 * HH * WW);       // 32
    int G = in_sizes[1] / (S * 4);             // 16

    dim3 grid((unsigned)((size_t)S * G * HH));
    dim3 block(256);
    crop_resize_kernel<<<grid, block, 0, stream>>>(x, f, out, S, G);
}